// Round 12
// baseline (348.118 us; speedup 1.0000x reference)
//
#include <hip/hip_runtime.h>
#include <hip/hip_cooperative_groups.h>

namespace cg = cooperative_groups;

#define CLIP 4096
#define H1   2048
#define H2   1024
#define RN   4096
#define H_STEP 2.44140625f   // r_i = H_STEP*(i+1) exactly
#define G1   65536           // Sturm grid points per l (131072 chains = 2 waves/SIMD)

// ---- monotone float<->uint map for atomic min/max of floats -----------------
__device__ __forceinline__ unsigned fmap(float f) {
    unsigned u = __float_as_uint(f);
    return (u & 0x80000000u) ? ~u : (u | 0x80000000u);
}
__device__ __forceinline__ float funmap(unsigned u) {
    return __uint_as_float((u & 0x80000000u) ? (u & 0x7fffffffu) : ~u);
}
__device__ __forceinline__ void spect_bounds(const unsigned* bu, float& lo, float& cell) {
    float mn = funmap(bu[0]), mx = funmap(bu[1]);
    lo = mn - 1e-3f;                              // Gershgorin: lambda_min >= min ptl
    float hi = mx + 2.33554432f + 1e-3f;          // lambda_max <= max ptl + 2 + 2/r0^2
    cell = (hi - lo) * (1.0f / (float)G1);
}

// -------- Sturm step, sign-alternating transform (verified R11) --------------
#define STEP_B(dv)                                                         \
    {                                                                      \
        float tt = (dv) - X;                                               \
        float p = fmaf(tt, pm1, pm2);                                      \
        r = __builtin_amdgcn_alignbit(r, __float_as_uint(p), 31);          \
        pm2 = pm1; pm1 = p;                                                \
    }
#define STEP_A(dv)                                                         \
    {                                                                      \
        float tt = X - (dv);                                               \
        float p = fmaf(tt, pm1, pm2);                                      \
        r = __builtin_amdgcn_alignbit(r, __float_as_uint(p), 31);          \
        pm2 = pm1; pm1 = p;                                                \
    }
#define CNT16                                                              \
    {                                                                      \
        unsigned xx = ((r ^ (r >> 1)) ^ 0x5555u) & 0xFFFFu;                \
        cnt += (unsigned)__builtin_popcount(xx);                           \
    }
#define RENORM                                                             \
    {                                                                      \
        unsigned a1 = __float_as_uint(pm1) & 0x7fffffffu;                  \
        unsigned a2 = __float_as_uint(pm2) & 0x7fffffffu;                  \
        unsigned hm = a1 > a2 ? a1 : a2;                                   \
        int es = 254 - (int)(hm >> 23);                                    \
        es = es < 1 ? 1 : es;                                              \
        float sc = __uint_as_float((unsigned)es << 23);                    \
        pm1 *= sc; pm2 *= sc;                                              \
    }

// ============ ONE cooperative kernel: all 6 phases, 512 blocks x 256 =========
__global__ __launch_bounds__(256) void mega(
    const float* __restrict__ energy, const float* __restrict__ W1,
    const float* __restrict__ b1, const float* __restrict__ W2,
    const float* __restrict__ b2, const float* __restrict__ W3,
    const float* __restrict__ b3, float* __restrict__ out,
    float* __restrict__ partA, float* __restrict__ partB,
    float* __restrict__ D, unsigned* __restrict__ bu,
    int* __restrict__ counts)
{
    cg::grid_group grid = cg::this_grid();
    __shared__ alignas(16) float sh[RN];          // 16 KB, reused per phase
    const int bx = blockIdx.x, t = threadIdx.x;

    // ---- phase 1: layer-1 split-K partials (8 j-blocks x 64 k-chunks) ----
    if (bx == 0 && t == 0) { bu[0] = 0xFFFFFFFFu; bu[1] = 0u; }
    {
        int j = (bx & 7) * 256 + t, i0 = (bx >> 3) * 64;
        const float* Wp = W1 + (size_t)i0 * H1 + j;
        float acc = 0.f;
#pragma unroll 8
        for (int i = 0; i < 64; ++i)
            acc = fmaf(energy[i0 + i], Wp[(size_t)i * H1], acc);
        partA[(size_t)(bx >> 3) * H1 + j] = acc;
    }
    grid.sync();

    // ---- phase 2: layer-2 fused fin+GEMV (4 j-blocks x 128 k-chunks) ----
    {
        int i_loc = t >> 4, c_loc = t & 15, i0 = (bx >> 2) * 16;
        float s = 0.f;
#pragma unroll
        for (int k = 0; k < 4; ++k)
            s += partA[(size_t)(c_loc + 16 * k) * H1 + i0 + i_loc];
        s += __shfl_xor(s, 1); s += __shfl_xor(s, 2);
        s += __shfl_xor(s, 4); s += __shfl_xor(s, 8);
        if (c_loc == 0) sh[i_loc] = fmaxf(s + b1[i0 + i_loc], 0.f);
        __syncthreads();
        float xv[16];
#pragma unroll
        for (int u = 0; u < 16; ++u) xv[u] = sh[u];
        int j = (bx & 3) * 256 + t;
        const float* Wp = W2 + (size_t)i0 * H2 + j;
        float acc = 0.f;
#pragma unroll
        for (int i = 0; i < 16; ++i)
            acc = fmaf(xv[i], Wp[(size_t)i * H2], acc);
        partB[(size_t)(bx >> 2) * H2 + j] = acc;
    }
    grid.sync();

    // ---- phase 3: layer-3 fused fin+GEMV (16 j-blocks x 32 k-chunks) ----
    {
        int i_loc = t >> 3, c_loc = t & 7, i0 = (bx >> 4) * 32;
        float s = 0.f;
#pragma unroll
        for (int k = 0; k < 16; ++k)
            s += partB[(size_t)(c_loc + 8 * k) * H2 + i0 + i_loc];
        s += __shfl_xor(s, 1); s += __shfl_xor(s, 2); s += __shfl_xor(s, 4);
        if (c_loc == 0) sh[i_loc] = fmaxf(s + b2[i0 + i_loc], 0.f);
        __syncthreads();
        float xv[32];
#pragma unroll
        for (int u = 0; u < 32; ++u) xv[u] = sh[u];
        int j = (bx & 15) * 256 + t;
        const float* Wp = W3 + (size_t)i0 * RN + j;
        float acc = 0.f;
#pragma unroll
        for (int i = 0; i < 32; ++i)
            acc = fmaf(xv[i], Wp[(size_t)i * RN], acc);
        partA[(size_t)(bx >> 4) * RN + j] = acc;
    }
    grid.sync();

    // ---- phase 4: fin3 -> ptl, D0/D1, spectral bounds (blocks 0..15) ----
    if (bx < 16) {
        int j = bx * 256 + t;
        float s = b3[j];
#pragma unroll 8
        for (int c = 0; c < 32; ++c) s += partA[(size_t)c * RN + j];
        out[j] = s;                               // ptl -> d_out[0:RN]
        float rr = H_STEP * (float)(j + 1);
        float base = 2.0f + 2.0f * s;             // 2*(1 + ptl)
        D[j] = base;                              // l = 0
        D[RN + j] = base + 4.0f / (rr * rr);      // l = 1
        float mn = s, mx = s;
        for (int off = 32; off; off >>= 1) {
            mn = fminf(mn, __shfl_down(mn, off));
            mx = fmaxf(mx, __shfl_down(mx, off));
        }
        if ((t & 63) == 0) { sh[t >> 6] = mn; sh[8 + (t >> 6)] = mx; }
        __syncthreads();
        if (t == 0) {
            for (int w = 1; w < 4; ++w) { mn = fminf(mn, sh[w]); mx = fmaxf(mx, sh[8 + w]); }
            atomicMin(&bu[0], fmap(mn));
            atomicMax(&bu[1], fmap(mx));
        }
    }
    grid.sync();

    // ---- phase 5: Sturm counts (2 l-halves x 256 j-blocks) ----
    {
        int y = bx >> 8;                          // l
        const float* Dsrc = D + (y << 12);
        for (int i = t; i < RN / 4; i += 256)
            reinterpret_cast<float4*>(sh)[i] = reinterpret_cast<const float4*>(Dsrc)[i];
        __syncthreads();

        float lo, cell;
        spect_bounds(bu, lo, cell);
        int j = (bx & 255) * 256 + t;             // j < 65536
        float X = 2.0f * (lo + cell * (float)j);

        float pm1 = 1.0f, pm2 = 0.0f;             // u_0 = 1, u_{-1} = 0
        unsigned cnt = 0, r = 0;
        const float4* d4 = reinterpret_cast<const float4*>(sh);
        for (int w = 0; w < 32; ++w) {
            const float4* g = d4 + w * 32;
#pragma unroll
            for (int q = 0; q < 8; ++q) {
                float4 a = g[q * 4 + 0];
                float4 b2v = g[q * 4 + 1];
                float4 c2 = g[q * 4 + 2];
                float4 e2 = g[q * 4 + 3];
                STEP_B(a.x)   STEP_A(a.y)   STEP_B(a.z)   STEP_A(a.w)
                STEP_B(b2v.x) STEP_A(b2v.y) STEP_B(b2v.z) STEP_A(b2v.w)
                STEP_B(c2.x)  STEP_A(c2.y)  STEP_B(c2.z)  STEP_A(c2.w)
                STEP_B(e2.x)  STEP_A(e2.y)  STEP_B(e2.z)  STEP_A(e2.w)
                CNT16
                RENORM       // growth <= ~2^75 per 16 steps: safe in f32
            }
        }
        counts[(y << 16) + j] = (int)cnt;
    }
    grid.sync();

    // ---- phase 6: bracket search + midpoint (blocks 0..31) ----
    if (bx < 32) {
        int e = bx * 256 + t;                     // 8192 eigenvalues (l,k)
        int l = e >> 12, k = e & (RN - 1);
        const int* c = counts + (l << 16);
        int lo_i = 0, hi_i = G1 - 1;              // last j with c[j] <= k
        while (lo_i < hi_i) {
            int mid = (lo_i + hi_i + 1) >> 1;
            if (c[mid] <= k) lo_i = mid; else hi_i = mid - 1;
        }
        while (lo_i > 0 && c[lo_i] > k) --lo_i;   // +-1 noise fixups
        while (lo_i < G1 - 1 && c[lo_i + 1] <= k) ++lo_i;
        float lo, cell;
        spect_bounds(bu, lo, cell);
        out[RN + e] = lo + cell * ((float)lo_i + 0.5f);
    }
}

extern "C" void kernel_launch(void* const* d_in, const int* in_sizes, int n_in,
                              void* d_out, int out_size, void* d_ws, size_t ws_size,
                              hipStream_t stream) {
    const float* energy = (const float*)d_in[0];
    const float* W1 = (const float*)d_in[1];
    const float* b1 = (const float*)d_in[2];
    const float* W2 = (const float*)d_in[3];
    const float* b2 = (const float*)d_in[4];
    const float* W3 = (const float*)d_in[5];
    const float* b3 = (const float*)d_in[6];
    float* out = (float*)d_out;                   // [RN] ptl, then [2*RN] eigenvalues

    float* ws = (float*)d_ws;
    float*    partA  = ws;                        // 131072 f32 (layers 1,3)
    float*    partB  = partA + 131072;            // 131072 f32 (layer 2)
    float*    D      = partB + 131072;            // 2*RN f32 (D0 | D1)
    unsigned* bu     = (unsigned*)(D + 2 * RN);   // 2 u32
    int*      counts = (int*)(bu + 4);            // 2*G1 i32 (512 KB)

    void* args[] = {
        (void*)&energy, (void*)&W1, (void*)&b1, (void*)&W2, (void*)&b2,
        (void*)&W3, (void*)&b3, (void*)&out, (void*)&partA, (void*)&partB,
        (void*)&D, (void*)&bu, (void*)&counts
    };
    hipLaunchCooperativeKernel((void*)mega, dim3(512), dim3(256), args, 0, stream);
}

// Round 13
// 70.852 us; speedup vs baseline: 4.9133x; 4.9133x over previous
//
#include <hip/hip_runtime.h>

#define CLIP 4096
#define H1   2048
#define H2   1024
#define RN   4096
#define H_STEP 2.44140625f   // r_i = H_STEP*(i+1) exactly
#define G1   32768           // Sturm grid points per l (65536 chains = 1 wave/SIMD)

// ---- monotone float<->uint map for atomic min/max of floats -----------------
__device__ __forceinline__ unsigned fmap(float f) {
    unsigned u = __float_as_uint(f);
    return (u & 0x80000000u) ? ~u : (u | 0x80000000u);
}
__device__ __forceinline__ float funmap(unsigned u) {
    return __uint_as_float((u & 0x80000000u) ? (u & 0x7fffffffu) : ~u);
}
__device__ __forceinline__ void spect_bounds(const unsigned* bu, float& lo, float& cell) {
    float mn = funmap(bu[0]), mx = funmap(bu[1]);
    lo = mn - 1e-3f;                              // Gershgorin: lambda_min >= min ptl
    float hi = mx + 2.33554432f + 1e-3f;          // lambda_max <= max ptl + 2 + 2/r0^2
    cell = (hi - lo) * (1.0f / (float)G1);
}

// ---------------- Layer 1 split-K partials: partA[c][j] ----------------------
__global__ __launch_bounds__(256) void part1(const float* __restrict__ W,
                                             const float* __restrict__ x,
                                             float* __restrict__ partA,
                                             unsigned* __restrict__ bu) {
    if (blockIdx.x == 0 && blockIdx.y == 0 && threadIdx.x == 0) {
        bu[0] = 0xFFFFFFFFu;   // running min (mapped)
        bu[1] = 0u;            // running max (mapped)
    }
    int j = blockIdx.x * 256 + threadIdx.x;       // 8 x-blocks -> j < 2048
    int i0 = blockIdx.y * 64;                     // 64 k-chunks of 64 rows
    const float* Wp = W + (size_t)i0 * H1 + j;
    float acc = 0.f;
#pragma unroll 8
    for (int i = 0; i < 64; ++i)
        acc = fmaf(x[i0 + i], Wp[(size_t)i * H1], acc);   // x uniform -> s_load
    partA[(size_t)blockIdx.y * H1 + j] = acc;
}

// ------- Layer 2, fused: prologue reduces the 16 h1 values this block needs --
__global__ __launch_bounds__(256) void part2f(const float* __restrict__ W,
                                              const float* __restrict__ partA,
                                              const float* __restrict__ b,
                                              float* __restrict__ partB) {
    __shared__ float xs[16];
    int t = threadIdx.x;
    int i_loc = t >> 4, c_loc = t & 15;           // 16 i's x 16 lanes
    int i0 = blockIdx.y * 16;                     // 128 k-chunks of 16 rows
    float s = 0.f;
#pragma unroll
    for (int k = 0; k < 4; ++k)                   // 64 layer-1 partials
        s += partA[(size_t)(c_loc + 16 * k) * H1 + i0 + i_loc];
    s += __shfl_xor(s, 1); s += __shfl_xor(s, 2);
    s += __shfl_xor(s, 4); s += __shfl_xor(s, 8);
    if (c_loc == 0) xs[i_loc] = fmaxf(s + b[i0 + i_loc], 0.f);
    __syncthreads();
    float xv[16];
#pragma unroll
    for (int u = 0; u < 16; ++u) xv[u] = xs[u];
    int j = blockIdx.x * 256 + t;                 // 4 x-blocks -> j < 1024
    const float* Wp = W + (size_t)i0 * H2 + j;
    float acc = 0.f;
#pragma unroll
    for (int i = 0; i < 16; ++i)
        acc = fmaf(xv[i], Wp[(size_t)i * H2], acc);
    partB[(size_t)blockIdx.y * H2 + j] = acc;
}

// ------- Layer 3, fused: prologue reduces the 32 h2 values this block needs --
__global__ __launch_bounds__(256) void part3f(const float* __restrict__ W,
                                              const float* __restrict__ partB,
                                              const float* __restrict__ b,
                                              float* __restrict__ partA) {
    __shared__ float xs[32];
    int t = threadIdx.x;
    int i_loc = t >> 3, c_loc = t & 7;            // 32 i's x 8 lanes
    int i0 = blockIdx.y * 32;                     // 32 k-chunks of 32 rows
    float s = 0.f;
#pragma unroll
    for (int k = 0; k < 16; ++k)                  // 128 layer-2 partials
        s += partB[(size_t)(c_loc + 8 * k) * H2 + i0 + i_loc];
    s += __shfl_xor(s, 1); s += __shfl_xor(s, 2); s += __shfl_xor(s, 4);
    if (c_loc == 0) xs[i_loc] = fmaxf(s + b[i0 + i_loc], 0.f);
    __syncthreads();
    float xv[32];
#pragma unroll
    for (int u = 0; u < 32; ++u) xv[u] = xs[u];
    int j = blockIdx.x * 256 + t;                 // 16 x-blocks -> j < 4096
    const float* Wp = W + (size_t)i0 * RN + j;
    float acc = 0.f;
#pragma unroll
    for (int i = 0; i < 32; ++i)
        acc = fmaf(xv[i], Wp[(size_t)i * RN], acc);
    partA[(size_t)blockIdx.y * RN + j] = acc;
}

// ---- Final fin: ptl -> d_out, D0/D1 = 2*diag (contiguous), spectral bounds --
__global__ __launch_bounds__(256) void fin3(const float* __restrict__ partA,
                                            const float* __restrict__ b,
                                            float* __restrict__ out,
                                            float* __restrict__ D,
                                            unsigned* __restrict__ bu) {
    __shared__ float smn[4], smx[4];
    int j = blockIdx.x * 256 + threadIdx.x;
    float s = b[j];
#pragma unroll 8
    for (int c = 0; c < 32; ++c) s += partA[(size_t)c * RN + j];
    out[j] = s;                                   // ptl -> d_out[0:RN]
    float r = H_STEP * (float)(j + 1);
    float base = 2.0f + 2.0f * s;                 // 2*(1 + ptl)
    D[j] = base;                                  // l = 0
    D[RN + j] = base + 4.0f / (r * r);            // l = 1: + 2*l(l+1)/r^2
    float mn = s, mx = s;
    for (int off = 32; off; off >>= 1) {
        mn = fminf(mn, __shfl_down(mn, off));
        mx = fmaxf(mx, __shfl_down(mx, off));
    }
    int tid = threadIdx.x;
    if ((tid & 63) == 0) { smn[tid >> 6] = mn; smx[tid >> 6] = mx; }
    __syncthreads();
    if (tid == 0) {
        for (int w = 1; w < 4; ++w) { mn = fminf(mn, smn[w]); mx = fmaxf(mx, smx[w]); }
        atomicMin(&bu[0], fmap(mn));
        atomicMax(&bu[1], fmap(mx));
    }
}

// -------- Sturm count via sign-alternating transform (verified R11) ----------
// p_i = (d_i - X) p_{i-1} - p_{i-2}; u_i = sigma_i p_i (sigma = ++--) gives
// u_i = t'_i u_{i-1} + u_{i-2} with t' alternating (d-X)/(X-d): no negation.
// Sign changes of p recovered via constant mask 0x5555.
#define STEP_B(dv)                                                         \
    {                                                                      \
        float tt = (dv) - X;                                               \
        float p = fmaf(tt, pm1, pm2);                                      \
        r = __builtin_amdgcn_alignbit(r, __float_as_uint(p), 31);          \
        pm2 = pm1; pm1 = p;                                                \
    }
#define STEP_A(dv)                                                         \
    {                                                                      \
        float tt = X - (dv);                                               \
        float p = fmaf(tt, pm1, pm2);                                      \
        r = __builtin_amdgcn_alignbit(r, __float_as_uint(p), 31);          \
        pm2 = pm1; pm1 = p;                                                \
    }
#define CNT16                                                              \
    {                                                                      \
        unsigned xx = ((r ^ (r >> 1)) ^ 0x5555u) & 0xFFFFu;                \
        cnt += (unsigned)__builtin_popcount(xx);                           \
    }
#define RENORM                                                             \
    {                                                                      \
        unsigned a1 = __float_as_uint(pm1) & 0x7fffffffu;                  \
        unsigned a2 = __float_as_uint(pm2) & 0x7fffffffu;                  \
        unsigned hm = a1 > a2 ? a1 : a2;                                   \
        int es = 254 - (int)(hm >> 23);                                    \
        es = es < 1 ? 1 : es;                                              \
        float sc = __uint_as_float((unsigned)es << 23);                    \
        pm1 *= sc; pm2 *= sc;                                              \
    }
#define GRP16(v0, v1, v2, v3)                                              \
    {                                                                      \
        STEP_B(v0.x) STEP_A(v0.y) STEP_B(v0.z) STEP_A(v0.w)                \
        STEP_B(v1.x) STEP_A(v1.y) STEP_B(v1.z) STEP_A(v1.w)                \
        STEP_B(v2.x) STEP_A(v2.y) STEP_B(v2.z) STEP_A(v2.w)                \
        STEP_B(v3.x) STEP_A(v3.y) STEP_B(v3.z) STEP_A(v3.w)                \
        CNT16                                                              \
        RENORM                                                             \
    }

// 1 wave/SIMD at G1=32768: register ping-pong (load next 16-step group while
// computing current) covers ~120cy LDS latency with ~128cy of group compute.
__global__ __launch_bounds__(256) void stage1(const float* __restrict__ Dall,
                                              const unsigned* __restrict__ bu,
                                              int* __restrict__ counts) {
    __shared__ alignas(16) float ds[RN];
    const float* Dsrc = Dall + (blockIdx.y << 12);   // D0 | D1
    for (int i = threadIdx.x; i < RN / 4; i += 256)
        reinterpret_cast<float4*>(ds)[i] = reinterpret_cast<const float4*>(Dsrc)[i];
    __syncthreads();

    float lo, cell;
    spect_bounds(bu, lo, cell);
    int j = blockIdx.x * 256 + threadIdx.x;          // 128 x-blocks -> j < 32768
    float X = 2.0f * (lo + cell * (float)j);

    float pm1 = 1.0f, pm2 = 0.0f;                    // u_0 = 1, u_{-1} = 0
    unsigned cnt = 0, r = 0;
    const float4* d4 = reinterpret_cast<const float4*>(ds);

    float4 A0 = d4[0], A1 = d4[1], A2 = d4[2], A3 = d4[3];
    float4 B0, B1, B2, B3;
    // 256 groups of 16 steps; ping-pong A/B register sets.
    for (int g = 0; g < 256; g += 2) {
        int nb = ((g + 1) & 255) << 2;
        B0 = d4[nb]; B1 = d4[nb + 1]; B2 = d4[nb + 2]; B3 = d4[nb + 3];
        GRP16(A0, A1, A2, A3)
        int na = ((g + 2) & 255) << 2;               // wraps at end (unused load)
        A0 = d4[na]; A1 = d4[na + 1]; A2 = d4[na + 2]; A3 = d4[na + 3];
        GRP16(B0, B1, B2, B3)
    }
    counts[(blockIdx.y << 15) + j] = (int)cnt;
}

// ------------- final: bracket search (noise-tolerant) + midpoint -------------
__global__ __launch_bounds__(256) void final_eig(const int* __restrict__ counts,
                                                 const unsigned* __restrict__ bu,
                                                 float* __restrict__ out) {
    int e = blockIdx.x * 256 + threadIdx.x;       // 8192 eigenvalues (l,k)
    int l = e >> 12, k = e & (RN - 1);
    const int* c = counts + (l << 15);
    int lo_i = 0, hi_i = G1 - 1;                  // last j with c[j] <= k
    while (lo_i < hi_i) {
        int mid = (lo_i + hi_i + 1) >> 1;
        if (c[mid] <= k) lo_i = mid; else hi_i = mid - 1;
    }
    while (lo_i > 0 && c[lo_i] > k) --lo_i;       // +-1 noise fixups
    while (lo_i < G1 - 1 && c[lo_i + 1] <= k) ++lo_i;
    float lo, cell;
    spect_bounds(bu, lo, cell);
    out[e] = lo + cell * ((float)lo_i + 0.5f);
}

extern "C" void kernel_launch(void* const* d_in, const int* in_sizes, int n_in,
                              void* d_out, int out_size, void* d_ws, size_t ws_size,
                              hipStream_t stream) {
    const float* energy = (const float*)d_in[0];
    const float* W1 = (const float*)d_in[1];
    const float* b1 = (const float*)d_in[2];
    const float* W2 = (const float*)d_in[3];
    const float* b2 = (const float*)d_in[4];
    const float* W3 = (const float*)d_in[5];
    const float* b3 = (const float*)d_in[6];
    float* out = (float*)d_out;                   // [RN] ptl, then [2*RN] eigenvalues

    float* ws = (float*)d_ws;
    float*    partA  = ws;                        // 131072 f32 (layers 1,3)
    float*    partB  = partA + 131072;            // 131072 f32 (layer 2)
    float*    D      = partB + 131072;            // 2*RN f32 (D0 | D1)
    unsigned* bu     = (unsigned*)(D + 2 * RN);   // 2 u32
    int*      counts = (int*)(bu + 4);            // 2*G1 i32 (256 KB)

    // ---- MLP: 3 GEMVs, fins fused into next layer's prologue ----
    part1 <<<dim3(8, 64),  256, 0, stream>>>(W1, energy, partA, bu);
    part2f<<<dim3(4, 128), 256, 0, stream>>>(W2, partA, b1, partB);
    part3f<<<dim3(16, 32), 256, 0, stream>>>(W3, partB, b2, partA);
    fin3  <<<RN / 256,     256, 0, stream>>>(partA, b3, out, D, bu);

    // ---- Eigenvalues: single-stage f32 Sturm multisection ----
    stage1<<<dim3(G1 / 256, 2), 256, 0, stream>>>(D, bu, counts);
    final_eig<<<2 * RN / 256, 256, 0, stream>>>(counts, bu, out + RN);
}

// Round 14
// 58.574 us; speedup vs baseline: 5.9432x; 1.2096x over previous
//
#include <hip/hip_runtime.h>

#define CLIP 4096
#define H1   2048
#define H2   1024
#define RN   4096
#define H_STEP 2.44140625f   // r_i = H_STEP*(i+1) exactly
#define G1   32768           // Sturm grid points per l

// ---- monotone float<->uint map for atomic min/max of floats -----------------
__device__ __forceinline__ unsigned fmap(float f) {
    unsigned u = __float_as_uint(f);
    return (u & 0x80000000u) ? ~u : (u | 0x80000000u);
}
__device__ __forceinline__ float funmap(unsigned u) {
    return __uint_as_float((u & 0x80000000u) ? (u & 0x7fffffffu) : ~u);
}
__device__ __forceinline__ void spect_bounds(const unsigned* bu, float& lo, float& cell) {
    float mn = funmap(bu[0]), mx = funmap(bu[1]);
    lo = mn - 1e-3f;                              // Gershgorin: lambda_min >= min ptl
    float hi = mx + 2.33554432f + 1e-3f;          // lambda_max <= max ptl + 2 + 2/r0^2
    cell = (hi - lo) * (1.0f / (float)G1);
}

// ---------------- Layer 1 split-K partials: partA[c][j] ----------------------
__global__ __launch_bounds__(256) void part1(const float* __restrict__ W,
                                             const float* __restrict__ x,
                                             float* __restrict__ partA,
                                             unsigned* __restrict__ bu) {
    if (blockIdx.x == 0 && blockIdx.y == 0 && threadIdx.x == 0) {
        bu[0] = 0xFFFFFFFFu;   // running min (mapped)
        bu[1] = 0u;            // running max (mapped)
    }
    int j = blockIdx.x * 256 + threadIdx.x;       // 8 x-blocks -> j < 2048
    int i0 = blockIdx.y * 64;                     // 64 k-chunks of 64 rows
    const float* Wp = W + (size_t)i0 * H1 + j;
    float acc = 0.f;
#pragma unroll 8
    for (int i = 0; i < 64; ++i)
        acc = fmaf(x[i0 + i], Wp[(size_t)i * H1], acc);   // x uniform -> s_load
    partA[(size_t)blockIdx.y * H1 + j] = acc;
}

// ------- Layer 2, fused: prologue reduces the 16 h1 values this block needs --
__global__ __launch_bounds__(256) void part2f(const float* __restrict__ W,
                                              const float* __restrict__ partA,
                                              const float* __restrict__ b,
                                              float* __restrict__ partB) {
    __shared__ float xs[16];
    int t = threadIdx.x;
    int i_loc = t >> 4, c_loc = t & 15;           // 16 i's x 16 lanes
    int i0 = blockIdx.y * 16;                     // 128 k-chunks of 16 rows
    float s = 0.f;
#pragma unroll
    for (int k = 0; k < 4; ++k)                   // 64 layer-1 partials
        s += partA[(size_t)(c_loc + 16 * k) * H1 + i0 + i_loc];
    s += __shfl_xor(s, 1); s += __shfl_xor(s, 2);
    s += __shfl_xor(s, 4); s += __shfl_xor(s, 8);
    if (c_loc == 0) xs[i_loc] = fmaxf(s + b[i0 + i_loc], 0.f);
    __syncthreads();
    float xv[16];
#pragma unroll
    for (int u = 0; u < 16; ++u) xv[u] = xs[u];
    int j = blockIdx.x * 256 + t;                 // 4 x-blocks -> j < 1024
    const float* Wp = W + (size_t)i0 * H2 + j;
    float acc = 0.f;
#pragma unroll
    for (int i = 0; i < 16; ++i)
        acc = fmaf(xv[i], Wp[(size_t)i * H2], acc);
    partB[(size_t)blockIdx.y * H2 + j] = acc;
}

// ------- Layer 3, fused: prologue reduces the 32 h2 values this block needs --
__global__ __launch_bounds__(256) void part3f(const float* __restrict__ W,
                                              const float* __restrict__ partB,
                                              const float* __restrict__ b,
                                              float* __restrict__ partA) {
    __shared__ float xs[32];
    int t = threadIdx.x;
    int i_loc = t >> 3, c_loc = t & 7;            // 32 i's x 8 lanes
    int i0 = blockIdx.y * 32;                     // 32 k-chunks of 32 rows
    float s = 0.f;
#pragma unroll
    for (int k = 0; k < 16; ++k)                  // 128 layer-2 partials
        s += partB[(size_t)(c_loc + 8 * k) * H2 + i0 + i_loc];
    s += __shfl_xor(s, 1); s += __shfl_xor(s, 2); s += __shfl_xor(s, 4);
    if (c_loc == 0) xs[i_loc] = fmaxf(s + b[i0 + i_loc], 0.f);
    __syncthreads();
    float xv[32];
#pragma unroll
    for (int u = 0; u < 32; ++u) xv[u] = xs[u];
    int j = blockIdx.x * 256 + t;                 // 16 x-blocks -> j < 4096
    const float* Wp = W + (size_t)i0 * RN + j;
    float acc = 0.f;
#pragma unroll
    for (int i = 0; i < 32; ++i)
        acc = fmaf(xv[i], Wp[(size_t)i * RN], acc);
    partA[(size_t)blockIdx.y * RN + j] = acc;
}

// ---- Final fin: ptl -> d_out, D0/D1 = 2*diag (contiguous), spectral bounds --
__global__ __launch_bounds__(256) void fin3(const float* __restrict__ partA,
                                            const float* __restrict__ b,
                                            float* __restrict__ out,
                                            float* __restrict__ D,
                                            unsigned* __restrict__ bu) {
    __shared__ float smn[4], smx[4];
    int j = blockIdx.x * 256 + threadIdx.x;
    float s = b[j];
#pragma unroll 8
    for (int c = 0; c < 32; ++c) s += partA[(size_t)c * RN + j];
    out[j] = s;                                   // ptl -> d_out[0:RN]
    float r = H_STEP * (float)(j + 1);
    float base = 2.0f + 2.0f * s;                 // 2*(1 + ptl)
    D[j] = base;                                  // l = 0
    D[RN + j] = base + 4.0f / (r * r);            // l = 1: + 2*l(l+1)/r^2
    float mn = s, mx = s;
    for (int off = 32; off; off >>= 1) {
        mn = fminf(mn, __shfl_down(mn, off));
        mx = fmaxf(mx, __shfl_down(mx, off));
    }
    int tid = threadIdx.x;
    if ((tid & 63) == 0) { smn[tid >> 6] = mn; smx[tid >> 6] = mx; }
    __syncthreads();
    if (tid == 0) {
        for (int w = 1; w < 4; ++w) { mn = fminf(mn, smn[w]); mx = fmaxf(mx, smx[w]); }
        atomicMin(&bu[0], fmap(mn));
        atomicMax(&bu[1], fmap(mx));
    }
}

// -------- Sturm count via sign-alternating transform (verified R11) ----------
// u'_k = t'_k u'_{k-1} + u'_{k-2}, t' alternating (D-X)/(X-D); mask 0x5555.
#define STEP_B(dv)                                                         \
    {                                                                      \
        float tt = (dv) - X;                                               \
        float p = fmaf(tt, pm1, pm2);                                      \
        r = __builtin_amdgcn_alignbit(r, __float_as_uint(p), 31);          \
        pm2 = pm1; pm1 = p;                                                \
    }
#define STEP_A(dv)                                                         \
    {                                                                      \
        float tt = X - (dv);                                               \
        float p = fmaf(tt, pm1, pm2);                                      \
        r = __builtin_amdgcn_alignbit(r, __float_as_uint(p), 31);          \
        pm2 = pm1; pm1 = p;                                                \
    }
#define CNT16                                                              \
    {                                                                      \
        unsigned xx = ((r ^ (r >> 1)) ^ 0x5555u) & 0xFFFFu;                \
        cnt += (unsigned)__builtin_popcount(xx);                           \
    }
#define RENORM                                                             \
    {                                                                      \
        unsigned a1 = __float_as_uint(pm1) & 0x7fffffffu;                  \
        unsigned a2 = __float_as_uint(pm2) & 0x7fffffffu;                  \
        unsigned hm = a1 > a2 ? a1 : a2;                                   \
        int es = 254 - (int)(hm >> 23);                                    \
        es = es < 1 ? 1 : es;                                              \
        float sc = __uint_as_float((unsigned)es << 23);                    \
        pm1 *= sc; pm2 *= sc;                                              \
    }
#define GRP16(v0, v1, v2, v3)                                              \
    {                                                                      \
        STEP_B(v0.x) STEP_A(v0.y) STEP_B(v0.z) STEP_A(v0.w)                \
        STEP_B(v1.x) STEP_A(v1.y) STEP_B(v1.z) STEP_A(v1.w)                \
        STEP_B(v2.x) STEP_A(v2.y) STEP_B(v2.z) STEP_A(v2.w)                \
        STEP_B(v3.x) STEP_A(v3.y) STEP_B(v3.z) STEP_A(v3.w)                \
        CNT16                                                              \
        RENORM                                                             \
    }
#define GRP16R(q3, q2, q1, q0)                                             \
    {                                                                      \
        STEP_B(q3.w) STEP_A(q3.z) STEP_B(q3.y) STEP_A(q3.x)                \
        STEP_B(q2.w) STEP_A(q2.z) STEP_B(q2.y) STEP_A(q2.x)                \
        STEP_B(q1.w) STEP_A(q1.z) STEP_B(q1.y) STEP_A(q1.x)                \
        STEP_B(q0.w) STEP_A(q0.z) STEP_B(q0.y) STEP_A(q0.x)                \
        CNT16                                                              \
        RENORM                                                             \
    }

// Twisted-factorization bidirectional Sturm: per block, 128 X-values x 2 dirs.
// Waves 0-1: forward u-chain (2048 steps, D[0..2047]); waves 2-3: backward
// w-chain (2047 steps, D[4095..2049]). count = SCfwd + SCbwd + [gamma_m < 0],
// gamma from both ends' final values at twist m=2048. 2048 waves = 2/SIMD.
__global__ __launch_bounds__(256) void stage1(const float* __restrict__ Dall,
                                              const unsigned* __restrict__ bu,
                                              int* __restrict__ counts) {
    __shared__ alignas(16) float ds[RN];
    __shared__ float shB1[128], shB2[128];
    __shared__ int   shCB[128];
    const int t = threadIdx.x, l = blockIdx.y;
    const float* Dsrc = Dall + (l << 12);
    for (int i = t; i < RN / 4; i += 256)
        reinterpret_cast<float4*>(ds)[i] = reinterpret_cast<const float4*>(Dsrc)[i];
    __syncthreads();

    float lo, cell;
    spect_bounds(bu, lo, cell);
    int xi = t & 127, dir = t >> 7;               // dir wave-uniform (128 = 2 waves)
    int j = blockIdx.x * 128 + xi;                // 256 x-blocks -> j < 32768
    float X = 2.0f * (lo + cell * (float)j);

    float pm1 = 1.0f, pm2 = 0.0f;                 // u'_0 = 1, u'_{-1} = 0
    unsigned cnt = 0, r = 0;
    const float4* d4 = reinterpret_cast<const float4*>(ds);

    if (dir == 0) {
        // forward: 128 groups -> pm1 = u'_2048, pm2 = u'_2047
#pragma unroll 4
        for (int g = 0; g < 128; ++g) {
            float4 a = d4[4 * g], b2 = d4[4 * g + 1];
            float4 c2 = d4[4 * g + 2], e2 = d4[4 * g + 3];
            GRP16(a, b2, c2, e2)
        }
    } else {
        // backward: w_k = v_{4096-k}; 127 groups + 15-step tail
        // -> pm1 = w'_2047 (= +-v_2049), pm2 = w'_2046 (= +-v_2050)
#pragma unroll 4
        for (int g = 0; g < 127; ++g) {
            int base = 1020 - 4 * g;
            float4 a3 = d4[base + 3], a2 = d4[base + 2];
            float4 a1 = d4[base + 1], a0 = d4[base];
            GRP16R(a3, a2, a1, a0)
        }
        {   // tail k = 2033..2047: D[2063]..D[2049]; parity mask 0x2AAA
            float4 a = d4[515], b2 = d4[514], c2 = d4[513], e2 = d4[512];
            STEP_B(a.w)  STEP_A(a.z)  STEP_B(a.y)  STEP_A(a.x)
            STEP_B(b2.w) STEP_A(b2.z) STEP_B(b2.y) STEP_A(b2.x)
            STEP_B(c2.w) STEP_A(c2.z) STEP_B(c2.y) STEP_A(c2.x)
            STEP_B(e2.w) STEP_A(e2.z) STEP_B(e2.y)
            unsigned xx = ((r ^ (r >> 1)) ^ 0x2AAAu) & 0x7FFFu;
            cnt += (unsigned)__builtin_popcount(xx);
        }
        shB1[xi] = pm1; shB2[xi] = pm2; shCB[xi] = (int)cnt;
    }
    __syncthreads();
    if (dir == 0) {
        // twist combine at m=2048. sigma signs: u_2048=+u'1, u_2047=-u'2,
        // v_2049=-w'1, v_2050=-w'2 ->
        // gammaN = -(Dm-X)u'1w'1 - u'2w'1 + u'1w'2; [gamma<0] = !(sg^su^sw)
        float u1 = pm1, u2 = pm2;
        float w1 = shB1[xi], w2 = shB2[xi];
        float Dm = ds[2048];
        float gg = -(Dm - X) * u1 * w1 - u2 * w1 + u1 * w2;
        unsigned sx = (__float_as_uint(gg) ^ __float_as_uint(u1) ^
                       __float_as_uint(w1)) >> 31;
        counts[(l << 15) + j] = (int)(cnt + (unsigned)shCB[xi] + (sx ^ 1u));
    }
}

// ------------- final: bracket search (noise-tolerant) + midpoint -------------
__global__ __launch_bounds__(256) void final_eig(const int* __restrict__ counts,
                                                 const unsigned* __restrict__ bu,
                                                 float* __restrict__ out) {
    int e = blockIdx.x * 256 + threadIdx.x;       // 8192 eigenvalues (l,k)
    int l = e >> 12, k = e & (RN - 1);
    const int* c = counts + (l << 15);
    int lo_i = 0, hi_i = G1 - 1;                  // last j with c[j] <= k
    while (lo_i < hi_i) {
        int mid = (lo_i + hi_i + 1) >> 1;
        if (c[mid] <= k) lo_i = mid; else hi_i = mid - 1;
    }
    while (lo_i > 0 && c[lo_i] > k) --lo_i;       // +-1 noise fixups
    while (lo_i < G1 - 1 && c[lo_i + 1] <= k) ++lo_i;
    float lo, cell;
    spect_bounds(bu, lo, cell);
    out[e] = lo + cell * ((float)lo_i + 0.5f);
}

extern "C" void kernel_launch(void* const* d_in, const int* in_sizes, int n_in,
                              void* d_out, int out_size, void* d_ws, size_t ws_size,
                              hipStream_t stream) {
    const float* energy = (const float*)d_in[0];
    const float* W1 = (const float*)d_in[1];
    const float* b1 = (const float*)d_in[2];
    const float* W2 = (const float*)d_in[3];
    const float* b2 = (const float*)d_in[4];
    const float* W3 = (const float*)d_in[5];
    const float* b3 = (const float*)d_in[6];
    float* out = (float*)d_out;                   // [RN] ptl, then [2*RN] eigenvalues

    float* ws = (float*)d_ws;
    float*    partA  = ws;                        // 131072 f32 (layers 1,3)
    float*    partB  = partA + 131072;            // 131072 f32 (layer 2)
    float*    D      = partB + 131072;            // 2*RN f32 (D0 | D1)
    unsigned* bu     = (unsigned*)(D + 2 * RN);   // 2 u32
    int*      counts = (int*)(bu + 4);            // 2*G1 i32 (256 KB)

    // ---- MLP: 3 GEMVs, fins fused into next layer's prologue ----
    part1 <<<dim3(8, 64),  256, 0, stream>>>(W1, energy, partA, bu);
    part2f<<<dim3(4, 128), 256, 0, stream>>>(W2, partA, b1, partB);
    part3f<<<dim3(16, 32), 256, 0, stream>>>(W3, partB, b2, partA);
    fin3  <<<RN / 256,     256, 0, stream>>>(partA, b3, out, D, bu);

    // ---- Eigenvalues: bidirectional (twisted) Sturm, 2 waves/SIMD ----
    stage1<<<dim3(G1 / 128, 2), 256, 0, stream>>>(D, bu, counts);
    final_eig<<<2 * RN / 256, 256, 0, stream>>>(counts, bu, out + RN);
}